// Round 18
// baseline (153.813 us; speedup 1.0000x reference)
//
#include <hip/hip_runtime.h>
#include <cstdint>
#include <cstddef>

#define A_LEN  2048
#define D_DIM  512
#define NHEADS 4
#define HDIM   128
#define B_SZ   4
#define ROWS   8192
#define LN_EPS 1e-5f
#define KSPLIT 2
#define KCHUNK (A_LEN / KSPLIT)   // 1024
#define KTILE  64                 // staged per barrier; processed as 2x32
#define QBLK   128                // 4 waves x 32 q-rows
#define MP_BLOCKS 65536           // mask_pack portion of prep_kernel

typedef __bf16 bf16x8 __attribute__((ext_vector_type(8)));
typedef __bf16 bf16x4 __attribute__((ext_vector_type(4)));
typedef float  f32x4  __attribute__((ext_vector_type(4)));
typedef float  f32x16 __attribute__((ext_vector_type(16)));
typedef unsigned int uint32x2 __attribute__((ext_vector_type(2)));

// global_load_lds: 16B/lane, dest = wave-uniform LDS base + lane*16
#define GLOAD_LDS(g, l) __builtin_amdgcn_global_load_lds(                      \
    (__attribute__((address_space(1))) const void*)(const void*)(g),           \
    (__attribute__((address_space(3))) void*)(void*)(l), 16, 0, 0)

#if __has_builtin(__builtin_amdgcn_exp2f)
#define EXP2F(x) __builtin_amdgcn_exp2f(x)
#else
#define EXP2F(x) exp2f(x)
#endif

static __device__ __forceinline__ uint32_t pkbf(float a, float b) {
    union { __bf16 h[2]; uint32_t u; } t;
    t.h[0] = (__bf16)a; t.h[1] = (__bf16)b;
    return t.u;
}

// ---------------------------------------------------------------------------
// LayerNorm (optional swish), f32 OR bf16 in, bf16 or f32 out. 1 wave / row.
// ---------------------------------------------------------------------------
__global__ __launch_bounds__(256) void ln_kernel(
    const void* __restrict__ in, void* __restrict__ out,
    const float* __restrict__ w, const float* __restrict__ bvec,
    int do_swish, int in_bf16, int out_bf16)
{
    int row  = blockIdx.x * 4 + (threadIdx.x >> 6);
    int lane = threadIdx.x & 63;
    float v[8];
    if (in_bf16) {
        bf16x8 iv = *(const bf16x8*)((const __bf16*)in + (size_t)row * D_DIM + lane * 8);
#pragma unroll
        for (int j = 0; j < 8; ++j) v[j] = (float)iv[j];
    } else {
        const float* x = (const float*)in + (size_t)row * D_DIM + lane * 8;
        float4 a  = *(const float4*)x;
        float4 b4 = *(const float4*)(x + 4);
        v[0]=a.x; v[1]=a.y; v[2]=a.z; v[3]=a.w;
        v[4]=b4.x; v[5]=b4.y; v[6]=b4.z; v[7]=b4.w;
    }
    if (do_swish) {
#pragma unroll
        for (int j = 0; j < 8; ++j) v[j] = v[j] / (1.f + __expf(-v[j]));
    }
    float s = 0.f, s2 = 0.f;
#pragma unroll
    for (int j = 0; j < 8; ++j) { s += v[j]; s2 += v[j] * v[j]; }
#pragma unroll
    for (int off = 32; off; off >>= 1) {
        s  += __shfl_xor(s,  off);
        s2 += __shfl_xor(s2, off);
    }
    float mean = s * (1.f / D_DIM);
    float var  = s2 * (1.f / D_DIM) - mean * mean;
    float inv  = rsqrtf(var + LN_EPS);
    const float* wp = w + lane * 8;
    const float* bp = bvec + lane * 8;
    float r[8];
#pragma unroll
    for (int j = 0; j < 8; ++j) r[j] = (v[j] - mean) * inv * wp[j] + bp[j];
    if (out_bf16) {
        bf16x8 ov;
#pragma unroll
        for (int j = 0; j < 8; ++j) ov[j] = (__bf16)r[j];
        *(bf16x8*)((__bf16*)out + (size_t)row * D_DIM + lane * 8) = ov;
    } else {
        float* o = (float*)out + (size_t)row * D_DIM + lane * 8;
        float4 o0 = {r[0], r[1], r[2], r[3]}, o1 = {r[4], r[5], r[6], r[7]};
        *(float4*)o = o0; *(float4*)(o + 4) = o1;
    }
}

// ---------------------------------------------------------------------------
// prep: blocks [0, MP_BLOCKS) pack connectivity -> MPT[b][k>>5][q];
//       blocks [MP_BLOCKS, +640) convert the 5 weights f32 -> bf16.
// ---------------------------------------------------------------------------
__global__ __launch_bounds__(256) void prep_kernel(
    const int* __restrict__ conn, uint32_t* __restrict__ mpt,
    const float* __restrict__ s0, const float* __restrict__ s1,
    const float* __restrict__ s2, const float* __restrict__ s3,
    const float* __restrict__ s4, __bf16* __restrict__ dst)
{
    int bid = blockIdx.x;
    if (bid < MP_BLOCKS) {
        size_t i = (size_t)bid * 256 + threadIdx.x;
        uint64_t bal = __ballot(conn[i] != 0);
        int lane = threadIdx.x & 63;
        int b  = (int)(i >> 22);
        int q  = (int)((i >> 11) & (A_LEN - 1));
        int k0 = (int)(i & (A_LEN - 1) & ~(size_t)63);
        if (lane == 0)
            mpt[((size_t)b * 64 + (k0 >> 5)) * A_LEN + q] = (uint32_t)bal;
        else if (lane == 1)
            mpt[((size_t)b * 64 + (k0 >> 5) + 1) * A_LEN + q] = (uint32_t)(bal >> 32);
    } else {
        int c = bid - MP_BLOCKS;              // 0..639
        int widx = c >> 7, blk = c & 127;
        const float* src = widx == 0 ? s0 : widx == 1 ? s1 : widx == 2 ? s2
                         : widx == 3 ? s3 : s4;
        size_t i = ((size_t)blk * 256 + threadIdx.x) * 8;
        float4 a = *(const float4*)(src + i);
        float4 b = *(const float4*)(src + i + 4);
        bf16x8 o;
        o[0]=(__bf16)a.x; o[1]=(__bf16)a.y; o[2]=(__bf16)a.z; o[3]=(__bf16)a.w;
        o[4]=(__bf16)b.x; o[5]=(__bf16)b.y; o[6]=(__bf16)b.z; o[7]=(__bf16)b.w;
        *(bf16x8*)(dst + (size_t)widx * D_DIM * D_DIM + i) = o;
    }
}

// ---------------------------------------------------------------------------
// Fused QKV GEMM (reg-staged). grid (12, M/128): x = weight*4+head (FASTEST),
// y = m-block -- 12 consecutive blocks share one A-tile (L2-hit) and the
// 1.5MB W set stays L2-resident; A streams from HBM once, not 12x.
// QSCALE includes log2(e).
// ---------------------------------------------------------------------------
#define GBM 128
#define GBK 32
#define GPAD 40

__global__ __launch_bounds__(256) void gemm_qkv(
    const __bf16* __restrict__ Am, const __bf16* __restrict__ Wall,
    __bf16* __restrict__ Qh, __bf16* __restrict__ Kh, __bf16* __restrict__ Vt2)
{
    const int K = D_DIM;
    __shared__ alignas(16) __bf16 As[2][GBM][GPAD];
    __shared__ alignas(16) __bf16 Ws[2][GBM][GPAD];
    int tid = threadIdx.x;
    int w = tid >> 6, lane = tid & 63;
    int grp = lane >> 4, col = lane & 15;
    int wr = w >> 1, wc = w & 1;
    int m0 = blockIdx.y * GBM;
    int widx = blockIdx.x >> 2;
    int h    = blockIdx.x & 3;
    const __bf16* Wm = Wall + (size_t)widx * D_DIM * D_DIM;
    int n0 = h * 128;

    int srow = tid >> 1;
    int skc  = (tid & 1) * 16;
    const __bf16* agp = Am + (size_t)(m0 + srow) * K + skc;
    const __bf16* wgp = Wm + (size_t)(n0 + srow) * K + skc;

    uint4 ar0, ar1, wr0, wr1;
    ar0 = *(const uint4*)agp;       ar1 = *(const uint4*)(agp + 8);
    wr0 = *(const uint4*)wgp;       wr1 = *(const uint4*)(wgp + 8);
    *(uint4*)&As[0][srow][skc] = ar0; *(uint4*)&As[0][srow][skc + 8] = ar1;
    *(uint4*)&Ws[0][srow][skc] = wr0; *(uint4*)&Ws[0][srow][skc + 8] = wr1;
    __syncthreads();

    f32x4 acc[4][4] = {};
#pragma unroll 1
    for (int t = 0; t < K / GBK; ++t) {
        int cur = t & 1;
        bool more = (t + 1) < K / GBK;
        if (more) {
            const __bf16* ap = agp + (size_t)(t + 1) * GBK;
            const __bf16* wp = wgp + (size_t)(t + 1) * GBK;
            ar0 = *(const uint4*)ap; ar1 = *(const uint4*)(ap + 8);
            wr0 = *(const uint4*)wp; wr1 = *(const uint4*)(wp + 8);
        }
        bf16x8 af[4], wf[4];
#pragma unroll
        for (int mt = 0; mt < 4; ++mt)
            af[mt] = *(const bf16x8*)&As[cur][wr * 64 + mt * 16 + col][grp * 8];
#pragma unroll
        for (int nt = 0; nt < 4; ++nt)
            wf[nt] = *(const bf16x8*)&Ws[cur][wc * 64 + nt * 16 + col][grp * 8];
        __builtin_amdgcn_s_setprio(1);
#pragma unroll
        for (int mt = 0; mt < 4; ++mt)
#pragma unroll
            for (int nt = 0; nt < 4; ++nt)
                acc[mt][nt] = __builtin_amdgcn_mfma_f32_16x16x32_bf16(
                    af[mt], wf[nt], acc[mt][nt], 0, 0, 0);
        __builtin_amdgcn_s_setprio(0);
        if (more) {
            int nb = cur ^ 1;
            *(uint4*)&As[nb][srow][skc] = ar0; *(uint4*)&As[nb][srow][skc + 8] = ar1;
            *(uint4*)&Ws[nb][srow][skc] = wr0; *(uint4*)&Ws[nb][srow][skc + 8] = wr1;
        }
        __syncthreads();
    }

    // 1/sqrt(128) * log2(e): attn computes P = exp2(S') = exp(S)
    const float QSCALE = 0.08838834764831845f * 1.4426950408889634f;
    if (widx == 2) {
#pragma unroll
        for (int mt = 0; mt < 4; ++mt) {
            int m = m0 + wr * 64 + mt * 16 + grp * 4;
            int b = m >> 11, a = m & (A_LEN - 1);
            int kt = a >> 5, k32 = a & 31;
            int bh = b * NHEADS + h;
#pragma unroll
            for (int nt = 0; nt < 4; ++nt) {
                int d = wc * 64 + nt * 16 + col;
                bf16x4 o;
                o[0] = (__bf16)acc[mt][nt][0]; o[1] = (__bf16)acc[mt][nt][1];
                o[2] = (__bf16)acc[mt][nt][2]; o[3] = (__bf16)acc[mt][nt][3];
                *(bf16x4*)(Vt2 + (((size_t)bh * 64 + kt) * HDIM + d) * 32 + k32) = o;
            }
        }
    } else {
        __bf16* Cb = widx == 0 ? Qh : Kh;
        float sc = widx == 0 ? QSCALE : 1.0f;
#pragma unroll
        for (int nt = 0; nt < 4; ++nt) {
            int d = wc * 64 + nt * 16 + col;
#pragma unroll
            for (int mt = 0; mt < 4; ++mt) {
#pragma unroll
                for (int r = 0; r < 4; ++r) {
                    int m = m0 + wr * 64 + mt * 16 + grp * 4 + r;
                    int b = m >> 11, a = m & (A_LEN - 1);
                    Cb[((size_t)(b * NHEADS + h) * A_LEN + a) * HDIM + d] =
                        (__bf16)(acc[mt][nt][r] * sc);
                }
            }
        }
    }
}

// ---------------------------------------------------------------------------
// fc GEMM (reg-staged): C bf16 = A bf16 * W^T bf16 + bias. 128x64 tile.
// grid (8, M/128): x = n-block (FASTEST) -- 8 consecutive blocks share one
// A-tile; W (0.5MB) L2-resident.
// ---------------------------------------------------------------------------
__global__ __launch_bounds__(256) void gemm_tile64(
    const __bf16* __restrict__ Am, const __bf16* __restrict__ Wm,
    const float* __restrict__ bias, __bf16* __restrict__ C)
{
    const int N = D_DIM, K = D_DIM;
    __shared__ alignas(16) __bf16 As[2][128][GPAD];
    __shared__ alignas(16) __bf16 Ws[2][64][GPAD];
    int tid = threadIdx.x;
    int w = tid >> 6, lane = tid & 63;
    int grp = lane >> 4, col = lane & 15;
    int m0 = blockIdx.y * 128;
    int n0 = blockIdx.x * 64;

    int srow = tid >> 1;                 // 0..127 (A stage)
    int skc  = (tid & 1) * 16;
    int wrow = tid >> 2;                 // 0..63  (W stage)
    int wkc  = (tid & 3) * 8;
    const __bf16* agp = Am + (size_t)(m0 + srow) * K + skc;
    const __bf16* wgp = Wm + (size_t)(n0 + wrow) * K + wkc;

    uint4 ar0, ar1, wv0;
    ar0 = *(const uint4*)agp;  ar1 = *(const uint4*)(agp + 8);
    wv0 = *(const uint4*)wgp;
    *(uint4*)&As[0][srow][skc] = ar0; *(uint4*)&As[0][srow][skc + 8] = ar1;
    *(uint4*)&Ws[0][wrow][wkc] = wv0;
    __syncthreads();

    f32x4 acc[2][4] = {};
#pragma unroll 1
    for (int t = 0; t < K / GBK; ++t) {
        int cur = t & 1;
        bool more = (t + 1) < K / GBK;
        if (more) {
            const __bf16* ap = agp + (size_t)(t + 1) * GBK;
            const __bf16* wp = wgp + (size_t)(t + 1) * GBK;
            ar0 = *(const uint4*)ap; ar1 = *(const uint4*)(ap + 8);
            wv0 = *(const uint4*)wp;
        }
        bf16x8 af[2], wf[4];
#pragma unroll
        for (int mt = 0; mt < 2; ++mt)
            af[mt] = *(const bf16x8*)&As[cur][w * 32 + mt * 16 + col][grp * 8];
#pragma unroll
        for (int nt = 0; nt < 4; ++nt)
            wf[nt] = *(const bf16x8*)&Ws[cur][nt * 16 + col][grp * 8];
        __builtin_amdgcn_s_setprio(1);
#pragma unroll
        for (int mt = 0; mt < 2; ++mt)
#pragma unroll
            for (int nt = 0; nt < 4; ++nt)
                acc[mt][nt] = __builtin_amdgcn_mfma_f32_16x16x32_bf16(
                    af[mt], wf[nt], acc[mt][nt], 0, 0, 0);
        __builtin_amdgcn_s_setprio(0);
        if (more) {
            int nb = cur ^ 1;
            *(uint4*)&As[nb][srow][skc] = ar0; *(uint4*)&As[nb][srow][skc + 8] = ar1;
            *(uint4*)&Ws[nb][wrow][wkc] = wv0;
        }
        __syncthreads();
    }

#pragma unroll
    for (int nt = 0; nt < 4; ++nt) {
        int n = n0 + nt * 16 + col;
        float bv = bias[n];
#pragma unroll
        for (int mt = 0; mt < 2; ++mt) {
#pragma unroll
            for (int r = 0; r < 4; ++r) {
                int m = m0 + w * 32 + mt * 16 + grp * 4 + r;
                C[(size_t)m * N + n] = (__bf16)(acc[mt][nt][r] + bv);
            }
        }
    }
}

// ---------------------------------------------------------------------------
// Flash attention (r16 body -- attn floor): swapped-QK^T mfma_32x32x16,
// fixed m=0, exp2 path, KTILE=64 via global_load_lds, single St chain
// (StA/StB split regressed twice: r11, r17).
// K swizzle chunk^(row&15); V swizzle chunk^((row>>1)&3).
// ---------------------------------------------------------------------------
__global__ __launch_bounds__(256, 2) void attn_mfma(
    const __bf16* __restrict__ Qh, const __bf16* __restrict__ Kh,
    const __bf16* __restrict__ Vt2, const uint32_t* __restrict__ MPT,
    __bf16* __restrict__ Opart, float* __restrict__ lsum)
{
    int flat = blockIdx.x;                       // 0..511
    int swz  = (flat & 7) * 64 + (flat >> 3);    // XCD = flat%8 owns 64 ids
    int qx    = swz & 15;
    int bh    = (swz >> 4) & 15;
    int split = swz >> 8;
    int b = bh >> 2;
    int ks0 = split * KCHUNK;
    int tid = threadIdx.x;
    int w = tid >> 6, lane = tid & 63;
    int c31 = lane & 31, hi = lane >> 5;
    int qw = qx * QBLK + w * 32;

    __shared__ alignas(16) __bf16 Klds[2][KTILE][128];       // 32 KB
    __shared__ alignas(16) __bf16 Vlds[2][2][HDIM][32];      // 32 KB

    bf16x8 qf[8];
    {
        const __bf16* qptr = Qh + ((size_t)bh * A_LEN + qw + c31) * HDIM + hi * 8;
#pragma unroll
        for (int s = 0; s < 8; ++s) qf[s] = *(const bf16x8*)(qptr + s * 16);
    }

    const __bf16* Ksrc = Kh + ((size_t)bh * A_LEN + ks0) * HDIM;
    const __bf16* Vsrc = Vt2 + ((size_t)bh * 64 + (ks0 >> 5)) * HDIM * 32;
    const uint32_t* mpq = MPT + ((size_t)b * 64 + (ks0 >> 5)) * A_LEN + qw + c31;
    int kxor = c31 & 15;
    int vsw  = (c31 >> 1) & 3;

    int kso[4];
#pragma unroll
    for (int j = 0; j < 4; ++j) {
        int krow = j * 16 + w * 4 + (lane >> 4);
        kso[j] = krow * HDIM + (((lane & 15) ^ (krow & 15)) * 8);
    }
    int vcs = (((lane & 3) ^ ((lane >> 3) & 3)) * 8);
    int vrow0 = w * 16 + (lane >> 2);

    float l_part = 0.f;
    f32x16 oacc[4];
#pragma unroll
    for (int dt = 0; dt < 4; ++dt)
#pragma unroll
        for (int j = 0; j < 16; ++j) oacc[dt][j] = 0.f;

    // prologue: stage tile 0 (64 keys) into buf 0
    {
        __bf16* kb = &Klds[0][0][0];
#pragma unroll
        for (int j = 0; j < 4; ++j)
            GLOAD_LDS(Ksrc + kso[j], kb + (size_t)(j * 16 + w * 4) * 128);
#pragma unroll
        for (int s2 = 0; s2 < 2; ++s2) {
            __bf16* vb = &Vlds[0][s2][0][0];
#pragma unroll
            for (int j = 0; j < 2; ++j)
                GLOAD_LDS(Vsrc + (size_t)s2 * 4096 + (size_t)(j * 64 + vrow0) * 32 + vcs,
                          vb + (size_t)(j * 64 + w * 16) * 32);
        }
    }
    __syncthreads();

    const int ntl = KCHUNK / KTILE;   // 16
#pragma unroll 1
    for (int t = 0; t < ntl; ++t) {
        int cur = t & 1;
        bool more = (t + 1) < ntl;
        if (more) {
            const __bf16* kp = Ksrc + (size_t)(t + 1) * KTILE * HDIM;
            const __bf16* vp = Vsrc + (size_t)(t + 1) * 2 * HDIM * 32;
            __bf16* kb = &Klds[cur ^ 1][0][0];
#pragma unroll
            for (int j = 0; j < 4; ++j)
                GLOAD_LDS(kp + kso[j], kb + (size_t)(j * 16 + w * 4) * 128);
#pragma unroll
            for (int s2 = 0; s2 < 2; ++s2) {
                __bf16* vb = &Vlds[cur ^ 1][s2][0][0];
#pragma unroll
                for (int j = 0; j < 2; ++j)
                    GLOAD_LDS(vp + (size_t)s2 * 4096 + (size_t)(j * 64 + vrow0) * 32 + vcs,
                              vb + (size_t)(j * 64 + w * 16) * 32);
            }
        }

        uint32_t mw0 = mpq[(size_t)(2 * t) * A_LEN];
        uint32_t mw1 = mpq[(size_t)(2 * t + 1) * A_LEN];

#pragma unroll
        for (int sub = 0; sub < 2; ++sub) {
            uint32_t mw = sub ? mw1 : mw0;

            // S^T = K Q : S[k=(r&3)+8*(r>>2)+4*hi][q=c31]
            f32x16 St;
#pragma unroll
            for (int j = 0; j < 16; ++j) St[j] = 0.f;
            __builtin_amdgcn_s_setprio(1);
#pragma unroll
            for (int s = 0; s < 8; ++s) {
                bf16x8 kf = *(const bf16x8*)
                    &Klds[cur][sub * 32 + c31][(((s << 1) | hi) ^ kxor) * 8];
                St = __builtin_amdgcn_mfma_f32_32x32x16_bf16(kf, qf[s], St, 0, 0, 0);
            }
            __builtin_amdgcn_s_setprio(0);

            // P = mask ? exp2(S) : 0  (S pre-scaled by log2e; fixed m=0)
#pragma unroll
            for (int r = 0; r < 16; ++r) {
                int kb = (r & 3) + 8 * (r >> 2) + 4 * hi;
                float e = EXP2F(St[r]);
                St[r] = ((mw >> kb) & 1u) ? e : 0.f;
                l_part += St[r];
            }

            // pack P -> bf16, cross-half exchange via permlane32_swap
            bf16x8 pa[2];
#pragma unroll
            for (int sf = 0; sf < 2; ++sf) {
                uint32_t pk01 = pkbf(St[sf*8+0], St[sf*8+1]);
                uint32_t pk23 = pkbf(St[sf*8+2], St[sf*8+3]);
                uint32_t pk45 = pkbf(St[sf*8+4], St[sf*8+5]);
                uint32_t pk67 = pkbf(St[sf*8+6], St[sf*8+7]);
                uint32x2 e0 = __builtin_amdgcn_permlane32_swap(pk01, pk45, false, false);
                uint32x2 e1 = __builtin_amdgcn_permlane32_swap(pk23, pk67, false, false);
                union { uint32_t u[4]; bf16x8 v; } fu;
                fu.u[0] = e0[0];
                fu.u[1] = e1[0];
                fu.u[2] = e0[1];
                fu.u[3] = e1[1];
                pa[sf] = fu.v;
            }

            // O += P V  (V read applies chunk^((row>>1)&3))
            __builtin_amdgcn_s_setprio(1);
#pragma unroll
            for (int dt = 0; dt < 4; ++dt) {
                const __bf16* vrow = &Vlds[cur][sub][dt * 32 + c31][0];
                bf16x8 v0 = *(const bf16x8*)(vrow + ((hi)     ^ vsw) * 8);
                bf16x8 v1 = *(const bf16x8*)(vrow + ((2 | hi) ^ vsw) * 8);
                oacc[dt] = __builtin_amdgcn_mfma_f32_32x32x16_bf16(pa[0], v0, oacc[dt], 0, 0, 0);
                oacc[dt] = __builtin_amdgcn_mfma_f32_32x32x16_bf16(pa[1], v1, oacc[dt], 0, 0, 0);
            }
            __builtin_amdgcn_s_setprio(0);
        }

        __syncthreads();   // drains vmcnt(0): tile t+1 resident in buf cur^1
    }

    float l_tot = l_part + __shfl_xor(l_part, 32);
    if (lane < 32)
        lsum[((size_t)split * 16 + bh) * A_LEN + qw + lane] = l_tot;

    __bf16* ob = Opart + (((size_t)split * 16 + bh) * A_LEN + qw) * HDIM;
#pragma unroll
    for (int r = 0; r < 16; ++r) {
        int ql = (r & 3) + 8 * (r >> 2) + 4 * hi;
#pragma unroll
        for (int dt = 0; dt < 4; ++dt)
            ob[(size_t)ql * HDIM + dt * 32 + c31] = (__bf16)oacc[dt][r];
    }
}

// ---------------------------------------------------------------------------
// Fused: merge KSPLIT=2 partials (m=0 => plain sum) + swish + LN(ln1) -> bf16
// ---------------------------------------------------------------------------
__global__ __launch_bounds__(256) void attn_merge_ln(
    const __bf16* __restrict__ Opart, const float* __restrict__ lsum,
    const float* __restrict__ lw, const float* __restrict__ lb,
    __bf16* __restrict__ xbout)
{
    int wv = threadIdx.x >> 6, lane = threadIdx.x & 63;
    int ridx = blockIdx.x * 4 + wv;          // 0..8191
    int b = ridx >> 11, a = ridx & (A_LEN - 1);
    int d512 = lane * 8;
    int h = d512 >> 7, d = d512 & 127;
    int bh = b * NHEADS + h;

    float l0 = lsum[(size_t)bh * A_LEN + a];
    float l1 = lsum[((size_t)16 + bh) * A_LEN + a];
    float inv = 1.f / (l0 + l1);

    bf16x8 v0 = *(const bf16x8*)(Opart + ((size_t)bh * A_LEN + a) * HDIM + d);
    bf16x8 v1 = *(const bf16x8*)(Opart + (((size_t)16 + bh) * A_LEN + a) * HDIM + d);
    float v[8];
#pragma unroll
    for (int j = 0; j < 8; ++j) {
        float o = ((float)v0[j] + (float)v1[j]) * inv;
        v[j] = o / (1.f + __expf(-o));       // swish
    }
    float s = 0.f, s2 = 0.f;
#pragma unroll
    for (int j = 0; j < 8; ++j) { s += v[j]; s2 += v[j] * v[j]; }
#pragma unroll
    for (int off = 32; off; off >>= 1) {
        s  += __shfl_xor(s,  off);
        s2 += __shfl_xor(s2, off);
    }
    float mean = s * (1.f / D_DIM);
    float var  = s2 * (1.f / D_DIM) - mean * mean;
    float rinv = rsqrtf(var + LN_EPS);
    bf16x8 ov;
#pragma unroll
    for (int j = 0; j < 8; ++j)
        ov[j] = (__bf16)((v[j] - mean) * rinv * lw[d512 + j] + lb[d512 + j]);
    *(bf16x8*)(xbout + (size_t)ridx * D_DIM + d512) = ov;
}

// ---------------------------------------------------------------------------
extern "C" void kernel_launch(void* const* d_in, const int* in_sizes, int n_in,
                              void* d_out, int out_size, void* d_ws, size_t ws_size,
                              hipStream_t stream)
{
    const float* x      = (const float*)d_in[0];
    const int*   conn   = (const int*)d_in[1];
    const float* Wq     = (const float*)d_in[2];
    const float* Wk     = (const float*)d_in[3];
    const float* Wv     = (const float*)d_in[4];
    const float* norm_w = (const float*)d_in[5];
    const float* norm_b = (const float*)d_in[6];
    const float* ln1_w  = (const float*)d_in[7];
    const float* ln1_b  = (const float*)d_in[8];
    const float* fc1_w  = (const float*)d_in[9];
    const float* fc1_b  = (const float*)d_in[10];
    const float* ln2_w  = (const float*)d_in[11];
    const float* ln2_b  = (const float*)d_in[12];
    const float* fc2_w  = (const float*)d_in[13];
    const float* fc2_b  = (const float*)d_in[14];
    float* out = (float*)d_out;

    char* wsb = (char*)d_ws;
    const size_t WELEM = (size_t)D_DIM * D_DIM;
    const size_t MB = (size_t)1 << 20;
    __bf16*   wall = (__bf16*)(wsb);                         // 5 weights bf16 [0,3)
    uint32_t* mpt = (uint32_t*)(wsb + 3 * MB);               // 2MB  [3,5)
    float*    lsm = (float*)(wsb + 5 * MB);                  // .25MB [5,6)
    __bf16*   xb  = (__bf16*)(wsb + 6 * MB);                 // 8MB  [6,14)
    __bf16*   Qh  = (__bf16*)(wsb + 14 * MB);                // 8MB  [14,22)
    __bf16*   Kh  = (__bf16*)(wsb + 22 * MB);                // 8MB  [22,30)
    __bf16*   Vt2 = (__bf16*)(wsb + 30 * MB);                // 8MB  [30,38)
    __bf16*   Op  = (__bf16*)(wsb + 38 * MB);                // 16MB [38,54)
    __bf16*   h1  = (__bf16*)(wsb + 14 * MB);                // 8MB alias Qh
    __bf16*   h2  = (__bf16*)(wsb + 22 * MB);                // 8MB alias Kh

    dim3 blk(256);
    dim3 lnGrid(ROWS / 4);
    dim3 prepGrid(MP_BLOCKS + 5 * (WELEM / 8 / 256));        // 65536 + 640
    dim3 qkvGrid(12, ROWS / GBM);                            // x fastest: A reuse
    dim3 fcGrid(D_DIM / 64, ROWS / 128);                     // x fastest: A reuse
    dim3 attnGrid(16 * 16 * KSPLIT);                         // 512 blocks, 1D
    dim3 mergeGrid(ROWS / 4);

    prep_kernel<<<prepGrid, blk, 0, stream>>>(conn, mpt, Wq, Wk, Wv, fc1_w, fc2_w, wall);
    ln_kernel<<<lnGrid, blk, 0, stream>>>(x, xb, norm_w, norm_b, 0, 0, 1);
    gemm_qkv<<<qkvGrid, blk, 0, stream>>>(xb, wall, Qh, Kh, Vt2);
    attn_mfma<<<attnGrid, blk, 0, stream>>>(Qh, Kh, Vt2, mpt, Op, lsm);
    attn_merge_ln<<<mergeGrid, blk, 0, stream>>>(Op, lsm, ln1_w, ln1_b, xb);
    gemm_tile64<<<fcGrid, blk, 0, stream>>>(xb, wall + 3 * WELEM, fc1_b, h1);
    ln_kernel<<<lnGrid, blk, 0, stream>>>(h1, xb, ln2_w, ln2_b, 1, 1, 1);
    gemm_tile64<<<fcGrid, blk, 0, stream>>>(xb, wall + 4 * WELEM, fc2_b, h2);
    ln_kernel<<<lnGrid, blk, 0, stream>>>(h2, out, norm_w, norm_b, 0, 1, 0);
}

// Round 19
// 142.527 us; speedup vs baseline: 1.0792x; 1.0792x over previous
//
#include <hip/hip_runtime.h>
#include <cstdint>
#include <cstddef>

#define A_LEN  2048
#define D_DIM  512
#define NHEADS 4
#define HDIM   128
#define B_SZ   4
#define ROWS   8192
#define LN_EPS 1e-5f
#define KSPLIT 2
#define KCHUNK (A_LEN / KSPLIT)   // 1024
#define KTILE  64                 // staged per barrier; processed as 2x32
#define QBLK   128                // 4 waves x 32 q-rows
#define MP_BLOCKS 65536           // mask_pack portion of prep_kernel

typedef __bf16 bf16x8 __attribute__((ext_vector_type(8)));
typedef __bf16 bf16x4 __attribute__((ext_vector_type(4)));
typedef float  f32x4  __attribute__((ext_vector_type(4)));
typedef float  f32x16 __attribute__((ext_vector_type(16)));
typedef unsigned int uint32x2 __attribute__((ext_vector_type(2)));

// global_load_lds: 16B/lane, dest = wave-uniform LDS base + lane*16
#define GLOAD_LDS(g, l) __builtin_amdgcn_global_load_lds(                      \
    (__attribute__((address_space(1))) const void*)(const void*)(g),           \
    (__attribute__((address_space(3))) void*)(void*)(l), 16, 0, 0)

#if __has_builtin(__builtin_amdgcn_exp2f)
#define EXP2F(x) __builtin_amdgcn_exp2f(x)
#else
#define EXP2F(x) exp2f(x)
#endif

static __device__ __forceinline__ uint32_t pkbf(float a, float b) {
    union { __bf16 h[2]; uint32_t u; } t;
    t.h[0] = (__bf16)a; t.h[1] = (__bf16)b;
    return t.u;
}

// ---------------------------------------------------------------------------
// LayerNorm (optional swish), f32 OR bf16 in, bf16 or f32 out. 1 wave / row.
// ---------------------------------------------------------------------------
__global__ __launch_bounds__(256) void ln_kernel(
    const void* __restrict__ in, void* __restrict__ out,
    const float* __restrict__ w, const float* __restrict__ bvec,
    int do_swish, int in_bf16, int out_bf16)
{
    int row  = blockIdx.x * 4 + (threadIdx.x >> 6);
    int lane = threadIdx.x & 63;
    float v[8];
    if (in_bf16) {
        bf16x8 iv = *(const bf16x8*)((const __bf16*)in + (size_t)row * D_DIM + lane * 8);
#pragma unroll
        for (int j = 0; j < 8; ++j) v[j] = (float)iv[j];
    } else {
        const float* x = (const float*)in + (size_t)row * D_DIM + lane * 8;
        float4 a  = *(const float4*)x;
        float4 b4 = *(const float4*)(x + 4);
        v[0]=a.x; v[1]=a.y; v[2]=a.z; v[3]=a.w;
        v[4]=b4.x; v[5]=b4.y; v[6]=b4.z; v[7]=b4.w;
    }
    if (do_swish) {
#pragma unroll
        for (int j = 0; j < 8; ++j) v[j] = v[j] / (1.f + __expf(-v[j]));
    }
    float s = 0.f, s2 = 0.f;
#pragma unroll
    for (int j = 0; j < 8; ++j) { s += v[j]; s2 += v[j] * v[j]; }
#pragma unroll
    for (int off = 32; off; off >>= 1) {
        s  += __shfl_xor(s,  off);
        s2 += __shfl_xor(s2, off);
    }
    float mean = s * (1.f / D_DIM);
    float var  = s2 * (1.f / D_DIM) - mean * mean;
    float inv  = rsqrtf(var + LN_EPS);
    const float* wp = w + lane * 8;
    const float* bp = bvec + lane * 8;
    float r[8];
#pragma unroll
    for (int j = 0; j < 8; ++j) r[j] = (v[j] - mean) * inv * wp[j] + bp[j];
    if (out_bf16) {
        bf16x8 ov;
#pragma unroll
        for (int j = 0; j < 8; ++j) ov[j] = (__bf16)r[j];
        *(bf16x8*)((__bf16*)out + (size_t)row * D_DIM + lane * 8) = ov;
    } else {
        float* o = (float*)out + (size_t)row * D_DIM + lane * 8;
        float4 o0 = {r[0], r[1], r[2], r[3]}, o1 = {r[4], r[5], r[6], r[7]};
        *(float4*)o = o0; *(float4*)(o + 4) = o1;
    }
}

// ---------------------------------------------------------------------------
// prep: blocks [0, MP_BLOCKS) pack connectivity -> MPT[b][k>>5][q];
//       blocks [MP_BLOCKS, +640) convert the 5 weights f32 -> bf16.
// ---------------------------------------------------------------------------
__global__ __launch_bounds__(256) void prep_kernel(
    const int* __restrict__ conn, uint32_t* __restrict__ mpt,
    const float* __restrict__ s0, const float* __restrict__ s1,
    const float* __restrict__ s2, const float* __restrict__ s3,
    const float* __restrict__ s4, __bf16* __restrict__ dst)
{
    int bid = blockIdx.x;
    if (bid < MP_BLOCKS) {
        size_t i = (size_t)bid * 256 + threadIdx.x;
        uint64_t bal = __ballot(conn[i] != 0);
        int lane = threadIdx.x & 63;
        int b  = (int)(i >> 22);
        int q  = (int)((i >> 11) & (A_LEN - 1));
        int k0 = (int)(i & (A_LEN - 1) & ~(size_t)63);
        if (lane == 0)
            mpt[((size_t)b * 64 + (k0 >> 5)) * A_LEN + q] = (uint32_t)bal;
        else if (lane == 1)
            mpt[((size_t)b * 64 + (k0 >> 5) + 1) * A_LEN + q] = (uint32_t)(bal >> 32);
    } else {
        int c = bid - MP_BLOCKS;              // 0..639
        int widx = c >> 7, blk = c & 127;
        const float* src = widx == 0 ? s0 : widx == 1 ? s1 : widx == 2 ? s2
                         : widx == 3 ? s3 : s4;
        size_t i = ((size_t)blk * 256 + threadIdx.x) * 8;
        float4 a = *(const float4*)(src + i);
        float4 b = *(const float4*)(src + i + 4);
        bf16x8 o;
        o[0]=(__bf16)a.x; o[1]=(__bf16)a.y; o[2]=(__bf16)a.z; o[3]=(__bf16)a.w;
        o[4]=(__bf16)b.x; o[5]=(__bf16)b.y; o[6]=(__bf16)b.z; o[7]=(__bf16)b.w;
        *(bf16x8*)(dst + (size_t)widx * D_DIM * D_DIM + i) = o;
    }
}

// ---------------------------------------------------------------------------
// Fused QKV GEMM (reg-staged). grid (M/128, 12) -- x = m-block FASTEST
// (r18 grid-swap regressed: A is L3-resident, swap scattered W/L2).
// QSCALE includes log2(e).
// ---------------------------------------------------------------------------
#define GBM 128
#define GBK 32
#define GPAD 40

__global__ __launch_bounds__(256) void gemm_qkv(
    const __bf16* __restrict__ Am, const __bf16* __restrict__ Wall,
    __bf16* __restrict__ Qh, __bf16* __restrict__ Kh, __bf16* __restrict__ Vt2)
{
    const int K = D_DIM;
    __shared__ alignas(16) __bf16 As[2][GBM][GPAD];
    __shared__ alignas(16) __bf16 Ws[2][GBM][GPAD];
    int tid = threadIdx.x;
    int w = tid >> 6, lane = tid & 63;
    int grp = lane >> 4, col = lane & 15;
    int wr = w >> 1, wc = w & 1;
    int m0 = blockIdx.x * GBM;
    int widx = blockIdx.y >> 2;
    int h    = blockIdx.y & 3;
    const __bf16* Wm = Wall + (size_t)widx * D_DIM * D_DIM;
    int n0 = h * 128;

    int srow = tid >> 1;
    int skc  = (tid & 1) * 16;
    const __bf16* agp = Am + (size_t)(m0 + srow) * K + skc;
    const __bf16* wgp = Wm + (size_t)(n0 + srow) * K + skc;

    uint4 ar0, ar1, wr0, wr1;
    ar0 = *(const uint4*)agp;       ar1 = *(const uint4*)(agp + 8);
    wr0 = *(const uint4*)wgp;       wr1 = *(const uint4*)(wgp + 8);
    *(uint4*)&As[0][srow][skc] = ar0; *(uint4*)&As[0][srow][skc + 8] = ar1;
    *(uint4*)&Ws[0][srow][skc] = wr0; *(uint4*)&Ws[0][srow][skc + 8] = wr1;
    __syncthreads();

    f32x4 acc[4][4] = {};
#pragma unroll 1
    for (int t = 0; t < K / GBK; ++t) {
        int cur = t & 1;
        bool more = (t + 1) < K / GBK;
        if (more) {
            const __bf16* ap = agp + (size_t)(t + 1) * GBK;
            const __bf16* wp = wgp + (size_t)(t + 1) * GBK;
            ar0 = *(const uint4*)ap; ar1 = *(const uint4*)(ap + 8);
            wr0 = *(const uint4*)wp; wr1 = *(const uint4*)(wp + 8);
        }
        bf16x8 af[4], wf[4];
#pragma unroll
        for (int mt = 0; mt < 4; ++mt)
            af[mt] = *(const bf16x8*)&As[cur][wr * 64 + mt * 16 + col][grp * 8];
#pragma unroll
        for (int nt = 0; nt < 4; ++nt)
            wf[nt] = *(const bf16x8*)&Ws[cur][wc * 64 + nt * 16 + col][grp * 8];
        __builtin_amdgcn_s_setprio(1);
#pragma unroll
        for (int mt = 0; mt < 4; ++mt)
#pragma unroll
            for (int nt = 0; nt < 4; ++nt)
                acc[mt][nt] = __builtin_amdgcn_mfma_f32_16x16x32_bf16(
                    af[mt], wf[nt], acc[mt][nt], 0, 0, 0);
        __builtin_amdgcn_s_setprio(0);
        if (more) {
            int nb = cur ^ 1;
            *(uint4*)&As[nb][srow][skc] = ar0; *(uint4*)&As[nb][srow][skc + 8] = ar1;
            *(uint4*)&Ws[nb][srow][skc] = wr0; *(uint4*)&Ws[nb][srow][skc + 8] = wr1;
        }
        __syncthreads();
    }

    // 1/sqrt(128) * log2(e): attn computes P = exp2(S') = exp(S)
    const float QSCALE = 0.08838834764831845f * 1.4426950408889634f;
    if (widx == 2) {
#pragma unroll
        for (int mt = 0; mt < 4; ++mt) {
            int m = m0 + wr * 64 + mt * 16 + grp * 4;
            int b = m >> 11, a = m & (A_LEN - 1);
            int kt = a >> 5, k32 = a & 31;
            int bh = b * NHEADS + h;
#pragma unroll
            for (int nt = 0; nt < 4; ++nt) {
                int d = wc * 64 + nt * 16 + col;
                bf16x4 o;
                o[0] = (__bf16)acc[mt][nt][0]; o[1] = (__bf16)acc[mt][nt][1];
                o[2] = (__bf16)acc[mt][nt][2]; o[3] = (__bf16)acc[mt][nt][3];
                *(bf16x4*)(Vt2 + (((size_t)bh * 64 + kt) * HDIM + d) * 32 + k32) = o;
            }
        }
    } else {
        __bf16* Cb = widx == 0 ? Qh : Kh;
        float sc = widx == 0 ? QSCALE : 1.0f;
#pragma unroll
        for (int nt = 0; nt < 4; ++nt) {
            int d = wc * 64 + nt * 16 + col;
#pragma unroll
            for (int mt = 0; mt < 4; ++mt) {
#pragma unroll
                for (int r = 0; r < 4; ++r) {
                    int m = m0 + wr * 64 + mt * 16 + grp * 4 + r;
                    int b = m >> 11, a = m & (A_LEN - 1);
                    Cb[((size_t)(b * NHEADS + h) * A_LEN + a) * HDIM + d] =
                        (__bf16)(acc[mt][nt][r] * sc);
                }
            }
        }
    }
}

// ---------------------------------------------------------------------------
// fc GEMM (reg-staged): C bf16 = A bf16 * W^T bf16 + bias. 128x64 tile.
// grid (M/128, 8) -- x = m-block fastest (r17 order).
// ---------------------------------------------------------------------------
__global__ __launch_bounds__(256) void gemm_tile64(
    const __bf16* __restrict__ Am, const __bf16* __restrict__ Wm,
    const float* __restrict__ bias, __bf16* __restrict__ C)
{
    const int N = D_DIM, K = D_DIM;
    __shared__ alignas(16) __bf16 As[2][128][GPAD];
    __shared__ alignas(16) __bf16 Ws[2][64][GPAD];
    int tid = threadIdx.x;
    int w = tid >> 6, lane = tid & 63;
    int grp = lane >> 4, col = lane & 15;
    int m0 = blockIdx.x * 128;
    int n0 = blockIdx.y * 64;

    int srow = tid >> 1;                 // 0..127 (A stage)
    int skc  = (tid & 1) * 16;
    int wrow = tid >> 2;                 // 0..63  (W stage)
    int wkc  = (tid & 3) * 8;
    const __bf16* agp = Am + (size_t)(m0 + srow) * K + skc;
    const __bf16* wgp = Wm + (size_t)(n0 + wrow) * K + wkc;

    uint4 ar0, ar1, wv0;
    ar0 = *(const uint4*)agp;  ar1 = *(const uint4*)(agp + 8);
    wv0 = *(const uint4*)wgp;
    *(uint4*)&As[0][srow][skc] = ar0; *(uint4*)&As[0][srow][skc + 8] = ar1;
    *(uint4*)&Ws[0][wrow][wkc] = wv0;
    __syncthreads();

    f32x4 acc[2][4] = {};
#pragma unroll 1
    for (int t = 0; t < K / GBK; ++t) {
        int cur = t & 1;
        bool more = (t + 1) < K / GBK;
        if (more) {
            const __bf16* ap = agp + (size_t)(t + 1) * GBK;
            const __bf16* wp = wgp + (size_t)(t + 1) * GBK;
            ar0 = *(const uint4*)ap; ar1 = *(const uint4*)(ap + 8);
            wv0 = *(const uint4*)wp;
        }
        bf16x8 af[2], wf[4];
#pragma unroll
        for (int mt = 0; mt < 2; ++mt)
            af[mt] = *(const bf16x8*)&As[cur][w * 32 + mt * 16 + col][grp * 8];
#pragma unroll
        for (int nt = 0; nt < 4; ++nt)
            wf[nt] = *(const bf16x8*)&Ws[cur][nt * 16 + col][grp * 8];
        __builtin_amdgcn_s_setprio(1);
#pragma unroll
        for (int mt = 0; mt < 2; ++mt)
#pragma unroll
            for (int nt = 0; nt < 4; ++nt)
                acc[mt][nt] = __builtin_amdgcn_mfma_f32_16x16x32_bf16(
                    af[mt], wf[nt], acc[mt][nt], 0, 0, 0);
        __builtin_amdgcn_s_setprio(0);
        if (more) {
            int nb = cur ^ 1;
            *(uint4*)&As[nb][srow][skc] = ar0; *(uint4*)&As[nb][srow][skc + 8] = ar1;
            *(uint4*)&Ws[nb][wrow][wkc] = wv0;
        }
        __syncthreads();
    }

#pragma unroll
    for (int nt = 0; nt < 4; ++nt) {
        int n = n0 + nt * 16 + col;
        float bv = bias[n];
#pragma unroll
        for (int mt = 0; mt < 2; ++mt) {
#pragma unroll
            for (int r = 0; r < 4; ++r) {
                int m = m0 + w * 32 + mt * 16 + grp * 4 + r;
                C[(size_t)m * N + n] = (__bf16)(acc[mt][nt][r] + bv);
            }
        }
    }
}

// ---------------------------------------------------------------------------
// Flash attention (r16 body -- measured floor): swapped-QK^T mfma_32x32x16,
// fixed m=0, exp2 path, KTILE=64 via global_load_lds, single St chain
// (StA/StB split regressed twice: r11, r17).
// K swizzle chunk^(row&15); V swizzle chunk^((row>>1)&3).
// ---------------------------------------------------------------------------
__global__ __launch_bounds__(256, 2) void attn_mfma(
    const __bf16* __restrict__ Qh, const __bf16* __restrict__ Kh,
    const __bf16* __restrict__ Vt2, const uint32_t* __restrict__ MPT,
    __bf16* __restrict__ Opart, float* __restrict__ lsum)
{
    int flat = blockIdx.x;                       // 0..511
    int swz  = (flat & 7) * 64 + (flat >> 3);    // XCD = flat%8 owns 64 ids
    int qx    = swz & 15;
    int bh    = (swz >> 4) & 15;
    int split = swz >> 8;
    int b = bh >> 2;
    int ks0 = split * KCHUNK;
    int tid = threadIdx.x;
    int w = tid >> 6, lane = tid & 63;
    int c31 = lane & 31, hi = lane >> 5;
    int qw = qx * QBLK + w * 32;

    __shared__ alignas(16) __bf16 Klds[2][KTILE][128];       // 32 KB
    __shared__ alignas(16) __bf16 Vlds[2][2][HDIM][32];      // 32 KB

    bf16x8 qf[8];
    {
        const __bf16* qptr = Qh + ((size_t)bh * A_LEN + qw + c31) * HDIM + hi * 8;
#pragma unroll
        for (int s = 0; s < 8; ++s) qf[s] = *(const bf16x8*)(qptr + s * 16);
    }

    const __bf16* Ksrc = Kh + ((size_t)bh * A_LEN + ks0) * HDIM;
    const __bf16* Vsrc = Vt2 + ((size_t)bh * 64 + (ks0 >> 5)) * HDIM * 32;
    const uint32_t* mpq = MPT + ((size_t)b * 64 + (ks0 >> 5)) * A_LEN + qw + c31;
    int kxor = c31 & 15;
    int vsw  = (c31 >> 1) & 3;

    int kso[4];
#pragma unroll
    for (int j = 0; j < 4; ++j) {
        int krow = j * 16 + w * 4 + (lane >> 4);
        kso[j] = krow * HDIM + (((lane & 15) ^ (krow & 15)) * 8);
    }
    int vcs = (((lane & 3) ^ ((lane >> 3) & 3)) * 8);
    int vrow0 = w * 16 + (lane >> 2);

    float l_part = 0.f;
    f32x16 oacc[4];
#pragma unroll
    for (int dt = 0; dt < 4; ++dt)
#pragma unroll
        for (int j = 0; j < 16; ++j) oacc[dt][j] = 0.f;

    // prologue: stage tile 0 (64 keys) into buf 0
    {
        __bf16* kb = &Klds[0][0][0];
#pragma unroll
        for (int j = 0; j < 4; ++j)
            GLOAD_LDS(Ksrc + kso[j], kb + (size_t)(j * 16 + w * 4) * 128);
#pragma unroll
        for (int s2 = 0; s2 < 2; ++s2) {
            __bf16* vb = &Vlds[0][s2][0][0];
#pragma unroll
            for (int j = 0; j < 2; ++j)
                GLOAD_LDS(Vsrc + (size_t)s2 * 4096 + (size_t)(j * 64 + vrow0) * 32 + vcs,
                          vb + (size_t)(j * 64 + w * 16) * 32);
        }
    }
    __syncthreads();

    const int ntl = KCHUNK / KTILE;   // 16
#pragma unroll 1
    for (int t = 0; t < ntl; ++t) {
        int cur = t & 1;
        bool more = (t + 1) < ntl;
        if (more) {
            const __bf16* kp = Ksrc + (size_t)(t + 1) * KTILE * HDIM;
            const __bf16* vp = Vsrc + (size_t)(t + 1) * 2 * HDIM * 32;
            __bf16* kb = &Klds[cur ^ 1][0][0];
#pragma unroll
            for (int j = 0; j < 4; ++j)
                GLOAD_LDS(kp + kso[j], kb + (size_t)(j * 16 + w * 4) * 128);
#pragma unroll
            for (int s2 = 0; s2 < 2; ++s2) {
                __bf16* vb = &Vlds[cur ^ 1][s2][0][0];
#pragma unroll
                for (int j = 0; j < 2; ++j)
                    GLOAD_LDS(vp + (size_t)s2 * 4096 + (size_t)(j * 64 + vrow0) * 32 + vcs,
                              vb + (size_t)(j * 64 + w * 16) * 32);
            }
        }

        uint32_t mw0 = mpq[(size_t)(2 * t) * A_LEN];
        uint32_t mw1 = mpq[(size_t)(2 * t + 1) * A_LEN];

#pragma unroll
        for (int sub = 0; sub < 2; ++sub) {
            uint32_t mw = sub ? mw1 : mw0;

            // S^T = K Q : S[k=(r&3)+8*(r>>2)+4*hi][q=c31]
            f32x16 St;
#pragma unroll
            for (int j = 0; j < 16; ++j) St[j] = 0.f;
            __builtin_amdgcn_s_setprio(1);
#pragma unroll
            for (int s = 0; s < 8; ++s) {
                bf16x8 kf = *(const bf16x8*)
                    &Klds[cur][sub * 32 + c31][(((s << 1) | hi) ^ kxor) * 8];
                St = __builtin_amdgcn_mfma_f32_32x32x16_bf16(kf, qf[s], St, 0, 0, 0);
            }
            __builtin_amdgcn_s_setprio(0);

            // P = mask ? exp2(S) : 0  (S pre-scaled by log2e; fixed m=0)
#pragma unroll
            for (int r = 0; r < 16; ++r) {
                int kb = (r & 3) + 8 * (r >> 2) + 4 * hi;
                float e = EXP2F(St[r]);
                St[r] = ((mw >> kb) & 1u) ? e : 0.f;
                l_part += St[r];
            }

            // pack P -> bf16, cross-half exchange via permlane32_swap
            bf16x8 pa[2];
#pragma unroll
            for (int sf = 0; sf < 2; ++sf) {
                uint32_t pk01 = pkbf(St[sf*8+0], St[sf*8+1]);
                uint32_t pk23 = pkbf(St[sf*8+2], St[sf*8+3]);
                uint32_t pk45 = pkbf(St[sf*8+4], St[sf*8+5]);
                uint32_t pk67 = pkbf(St[sf*8+6], St[sf*8+7]);
                uint32x2 e0 = __builtin_amdgcn_permlane32_swap(pk01, pk45, false, false);
                uint32x2 e1 = __builtin_amdgcn_permlane32_swap(pk23, pk67, false, false);
                union { uint32_t u[4]; bf16x8 v; } fu;
                fu.u[0] = e0[0];
                fu.u[1] = e1[0];
                fu.u[2] = e0[1];
                fu.u[3] = e1[1];
                pa[sf] = fu.v;
            }

            // O += P V  (V read applies chunk^((row>>1)&3))
            __builtin_amdgcn_s_setprio(1);
#pragma unroll
            for (int dt = 0; dt < 4; ++dt) {
                const __bf16* vrow = &Vlds[cur][sub][dt * 32 + c31][0];
                bf16x8 v0 = *(const bf16x8*)(vrow + ((hi)     ^ vsw) * 8);
                bf16x8 v1 = *(const bf16x8*)(vrow + ((2 | hi) ^ vsw) * 8);
                oacc[dt] = __builtin_amdgcn_mfma_f32_32x32x16_bf16(pa[0], v0, oacc[dt], 0, 0, 0);
                oacc[dt] = __builtin_amdgcn_mfma_f32_32x32x16_bf16(pa[1], v1, oacc[dt], 0, 0, 0);
            }
            __builtin_amdgcn_s_setprio(0);
        }

        __syncthreads();   // drains vmcnt(0): tile t+1 resident in buf cur^1
    }

    float l_tot = l_part + __shfl_xor(l_part, 32);
    if (lane < 32)
        lsum[((size_t)split * 16 + bh) * A_LEN + qw + lane] = l_tot;

    __bf16* ob = Opart + (((size_t)split * 16 + bh) * A_LEN + qw) * HDIM;
#pragma unroll
    for (int r = 0; r < 16; ++r) {
        int ql = (r & 3) + 8 * (r >> 2) + 4 * hi;
#pragma unroll
        for (int dt = 0; dt < 4; ++dt)
            ob[(size_t)ql * HDIM + dt * 32 + c31] = (__bf16)oacc[dt][r];
    }
}

// ---------------------------------------------------------------------------
// Fused: merge KSPLIT=2 partials (m=0 => plain sum) + swish + LN(ln1) -> bf16
// ---------------------------------------------------------------------------
__global__ __launch_bounds__(256) void attn_merge_ln(
    const __bf16* __restrict__ Opart, const float* __restrict__ lsum,
    const float* __restrict__ lw, const float* __restrict__ lb,
    __bf16* __restrict__ xbout)
{
    int wv = threadIdx.x >> 6, lane = threadIdx.x & 63;
    int ridx = blockIdx.x * 4 + wv;          // 0..8191
    int b = ridx >> 11, a = ridx & (A_LEN - 1);
    int d512 = lane * 8;
    int h = d512 >> 7, d = d512 & 127;
    int bh = b * NHEADS + h;

    float l0 = lsum[(size_t)bh * A_LEN + a];
    float l1 = lsum[((size_t)16 + bh) * A_LEN + a];
    float inv = 1.f / (l0 + l1);

    bf16x8 v0 = *(const bf16x8*)(Opart + ((size_t)bh * A_LEN + a) * HDIM + d);
    bf16x8 v1 = *(const bf16x8*)(Opart + (((size_t)16 + bh) * A_LEN + a) * HDIM + d);
    float v[8];
#pragma unroll
    for (int j = 0; j < 8; ++j) {
        float o = ((float)v0[j] + (float)v1[j]) * inv;
        v[j] = o / (1.f + __expf(-o));       // swish
    }
    float s = 0.f, s2 = 0.f;
#pragma unroll
    for (int j = 0; j < 8; ++j) { s += v[j]; s2 += v[j] * v[j]; }
#pragma unroll
    for (int off = 32; off; off >>= 1) {
        s  += __shfl_xor(s,  off);
        s2 += __shfl_xor(s2, off);
    }
    float mean = s * (1.f / D_DIM);
    float var  = s2 * (1.f / D_DIM) - mean * mean;
    float rinv = rsqrtf(var + LN_EPS);
    bf16x8 ov;
#pragma unroll
    for (int j = 0; j < 8; ++j)
        ov[j] = (__bf16)((v[j] - mean) * rinv * lw[d512 + j] + lb[d512 + j]);
    *(bf16x8*)(xbout + (size_t)ridx * D_DIM + d512) = ov;
}

// ---------------------------------------------------------------------------
extern "C" void kernel_launch(void* const* d_in, const int* in_sizes, int n_in,
                              void* d_out, int out_size, void* d_ws, size_t ws_size,
                              hipStream_t stream)
{
    const float* x      = (const float*)d_in[0];
    const int*   conn   = (const int*)d_in[1];
    const float* Wq     = (const float*)d_in[2];
    const float* Wk     = (const float*)d_in[3];
    const float* Wv     = (const float*)d_in[4];
    const float* norm_w = (const float*)d_in[5];
    const float* norm_b = (const float*)d_in[6];
    const float* ln1_w  = (const float*)d_in[7];
    const float* ln1_b  = (const float*)d_in[8];
    const float* fc1_w  = (const float*)d_in[9];
    const float* fc1_b  = (const float*)d_in[10];
    const float* ln2_w  = (const float*)d_in[11];
    const float* ln2_b  = (const float*)d_in[12];
    const float* fc2_w  = (const float*)d_in[13];
    const float* fc2_b  = (const float*)d_in[14];
    float* out = (float*)d_out;

    char* wsb = (char*)d_ws;
    const size_t WELEM = (size_t)D_DIM * D_DIM;
    const size_t MB = (size_t)1 << 20;
    __bf16*   wall = (__bf16*)(wsb);                         // 5 weights bf16 [0,3)
    uint32_t* mpt = (uint32_t*)(wsb + 3 * MB);               // 2MB  [3,5)
    float*    lsm = (float*)(wsb + 5 * MB);                  // .25MB [5,6)
    __bf16*   xb  = (__bf16*)(wsb + 6 * MB);                 // 8MB  [6,14)
    __bf16*   Qh  = (__bf16*)(wsb + 14 * MB);                // 8MB  [14,22)
    __bf16*   Kh  = (__bf16*)(wsb + 22 * MB);                // 8MB  [22,30)
    __bf16*   Vt2 = (__bf16*)(wsb + 30 * MB);                // 8MB  [30,38)
    __bf16*   Op  = (__bf16*)(wsb + 38 * MB);                // 16MB [38,54)
    __bf16*   h1  = (__bf16*)(wsb + 14 * MB);                // 8MB alias Qh
    __bf16*   h2  = (__bf16*)(wsb + 22 * MB);                // 8MB alias Kh

    dim3 blk(256);
    dim3 lnGrid(ROWS / 4);
    dim3 prepGrid(MP_BLOCKS + 5 * (WELEM / 8 / 256));        // 65536 + 640
    dim3 qkvGrid(ROWS / GBM, 12);                            // x=m fastest
    dim3 fcGrid(ROWS / 128, D_DIM / 64);                     // x=m fastest
    dim3 attnGrid(16 * 16 * KSPLIT);                         // 512 blocks, 1D
    dim3 mergeGrid(ROWS / 4);

    prep_kernel<<<prepGrid, blk, 0, stream>>>(conn, mpt, Wq, Wk, Wv, fc1_w, fc2_w, wall);
    ln_kernel<<<lnGrid, blk, 0, stream>>>(x, xb, norm_w, norm_b, 0, 0, 1);
    gemm_qkv<<<qkvGrid, blk, 0, stream>>>(xb, wall, Qh, Kh, Vt2);
    attn_mfma<<<attnGrid, blk, 0, stream>>>(Qh, Kh, Vt2, mpt, Op, lsm);
    attn_merge_ln<<<mergeGrid, blk, 0, stream>>>(Op, lsm, ln1_w, ln1_b, xb);
    gemm_tile64<<<fcGrid, blk, 0, stream>>>(xb, wall + 3 * WELEM, fc1_b, h1);
    ln_kernel<<<lnGrid, blk, 0, stream>>>(h1, xb, ln2_w, ln2_b, 1, 1, 1);
    gemm_tile64<<<fcGrid, blk, 0, stream>>>(xb, wall + 4 * WELEM, fc2_b, h2);
    ln_kernel<<<lnGrid, blk, 0, stream>>>(h2, out, norm_w, norm_b, 0, 1, 0);
}